// Round 1
// baseline (72.382 us; speedup 1.0000x reference)
//
#include <hip/hip_runtime.h>
#include <math.h>

// VisualImitation1: the reference's 8 x 1000 x 1000 sign-mask / conv / max
// pipeline collapses analytically:
//   myact = sign (tanhf saturates to exactly +-1.0f),
//   mask after {-1,1}->{1,0} map + transpose is a plus-cross with a hole at
//   (ja=floor(z_pos[n,0]*1000), ib=floor(z_pos[n,1]*1000)),
//   plus-conv hits 4 only at that center (interior centers only),
//   relu(conv-3) = single 1.0 pixel per sample n.
// Output I_hat[1000,1000,10] is all zeros except <=8 pixels at
// (ja_n, ib_n, z_cls[n]). So: memset 40 MB + 8-thread fixup.
// The fixup computes the center conv through the faithful tanhf chain so any
// marginally-unsaturated input still produces the reference's center value.

#define SIZE 1000
#define NCLS 10

__device__ __forceinline__ float myact(float x) { return tanhf(x * 100000.0f); }

__device__ __forceinline__ float mapped_val(float a, float b, int y, int x) {
    // mask_T[y][x] = myact(y1[x]*x1[y]) * myact(y3[x]*x3[y]); then {-1,1}->{1,0}
    float x1 = myact(a - (float)y);        // gx1 = 0..999
    float x3 = myact(a - (float)(y + 1));  // gx3 = 1..1000
    float y1 = myact(b - (float)(x + 1));  // gy1 = 1..1000
    float y3 = myact(b - (float)x);        // gy3 = 0..999
    float m1 = myact(y1 * x1);
    float m3 = myact(y3 * x3);
    float M  = m1 * m3;
    return (M - 1.0f) * 0.5f * -1.0f;
}

__global__ void fixup_kernel(const float* __restrict__ z_pos,
                             const int* __restrict__ z_cls,
                             float* __restrict__ out, int n) {
    int t = threadIdx.x;
    if (t >= n) return;
    float a = z_pos[2 * t + 0] * 1000.0f;
    float b = z_pos[2 * t + 1] * 1000.0f;
    int ja = (int)floorf(a);
    int ib = (int)floorf(b);
    // Boundary centers lose a neighbor -> conv<=3 -> relu=0 (matches SAME pad).
    if (ja < 1 || ja > SIZE - 2 || ib < 1 || ib > SIZE - 2) return;
    float conv = mapped_val(a, b, ja - 1, ib) + mapped_val(a, b, ja + 1, ib) +
                 mapped_val(a, b, ja, ib - 1) + mapped_val(a, b, ja, ib + 1);
    float val = conv - 3.0f;  // relu
    if (val > 0.0f) {
        int cls = z_cls[t];
        out[(ja * SIZE + ib) * NCLS + cls] = val;
    }
}

extern "C" void kernel_launch(void* const* d_in, const int* in_sizes, int n_in,
                              void* d_out, int out_size, void* d_ws, size_t ws_size,
                              hipStream_t stream) {
    const float* z_pos = (const float*)d_in[0];   // [8,2] float32
    const int* z_cls   = (const int*)d_in[1];     // [8] int32
    float* out = (float*)d_out;                   // [1000,1000,10] float32

    int n = in_sizes[1];  // number of samples (8)

    // Zero the whole output (harness poisons it to 0xAA before every launch).
    hipMemsetAsync(out, 0, (size_t)out_size * sizeof(float), stream);

    // Light up the <=8 nonzero pixels.
    fixup_kernel<<<1, 64, 0, stream>>>(z_pos, z_cls, out, n);
}